// Round 2
// baseline (649.706 us; speedup 1.0000x reference)
//
#include <hip/hip_runtime.h>

typedef unsigned short u16;
typedef __attribute__((ext_vector_type(4))) float floatx4;
typedef __attribute__((ext_vector_type(8))) __bf16 bf16x8;
typedef __attribute__((ext_vector_type(4))) unsigned short us4;
typedef __attribute__((ext_vector_type(8))) unsigned short us8;

static __device__ __forceinline__ float b2f(u16 v) {
    union { unsigned u; float f; } x; x.u = ((unsigned)v) << 16; return x.f;
}
static __device__ __forceinline__ u16 f2b(float f) {
    union { float f; unsigned u; } x; x.f = f;
    unsigned u = x.u;
    return (u16)((u + 0x7fffu + ((u >> 16) & 1u)) >> 16);
}

#define GLOAD_LDS16(g, l) __builtin_amdgcn_global_load_lds( \
    (const __attribute__((address_space(1))) void*)(g),     \
    (__attribute__((address_space(3))) void*)(l), 16, 0, 0)

// ---------------- dtype detection ----------------
// Even u16 indices of a float32 array are mantissa garbage (log-uniform as
// bf16, ~50%/elem chance of |x|>=1). Of a bf16 array (this problem: all
// |values| < ~6) they are small. Any |bf16(bits)| >= 1.0 => tensor is fp32.
__global__ __launch_bounds__(1024) void detect_f32(
    const u16* p0, const u16* p1, const u16* p2, const u16* p3, const u16* p4,
    int n0, int n1, int n2, int n3, int n4, int* __restrict__ flags) {
    const u16* P[5] = {p0, p1, p2, p3, p4};
    int N[5] = {n0, n1, n2, n3, n4};
    const int b = blockIdx.x;
    const u16* p = P[b];
    const int n = N[b];
    __shared__ int any;
    if (threadIdx.x == 0) any = 0;
    __syncthreads();
    int found = 0;
    for (int j = threadIdx.x; 2 * j < n; j += 1024) {
        unsigned v = p[2 * j] & 0x7fffu;
        if (v >= 0x3f80u) found = 1;   // |bf16| >= 1.0 (incl. inf/nan)
    }
    if (found) atomicOr(&any, 1);
    __syncthreads();
    if (threadIdx.x == 0) flags[b] = any;
}

// ---------------- convert to internal bf16 ----------------
__global__ __launch_bounds__(256) void cvt_to_bf16(const void* __restrict__ src,
                                                   const int* __restrict__ flag,
                                                   u16* __restrict__ dstp, int nelem) {
    int i = (blockIdx.x * 256 + threadIdx.x) * 8;
    if (i >= nelem) return;
    if (*flag) {
        const float* s = (const float*)src;
        us8 o;
#pragma unroll
        for (int k = 0; k < 8; ++k) o[k] = f2b(s[i + k]);
        *(us8*)(dstp + i) = o;
    } else {
        *(us8*)(dstp + i) = *(const us8*)((const u16*)src + i);
    }
}

// W [K,N] row-major (fp32 or bf16) -> Wt [N,K] bf16. K,N multiples of 32.
__global__ __launch_bounds__(256) void cvt_wt(const void* __restrict__ W,
                                              const int* __restrict__ flag,
                                              u16* __restrict__ Wt, int K, int N) {
    __shared__ u16 tile[32][33];
    const int bx = blockIdx.x * 32;  // n
    const int by = blockIdx.y * 32;  // k
    const int tx = threadIdx.x & 31, ty = threadIdx.x >> 5;
    const int f = *flag;
    for (int i = ty; i < 32; i += 8) {
        long idx = (long)(by + i) * N + (bx + tx);
        tile[i][tx] = f ? f2b(((const float*)W)[idx]) : ((const u16*)W)[idx];
    }
    __syncthreads();
    for (int i = ty; i < 32; i += 8)
        Wt[(long)(bx + i) * K + (by + tx)] = tile[tx][i];
}

// ---------------- CSR build ----------------
__global__ void count_deg(const int* __restrict__ dst, int E, int Nn,
                          int* __restrict__ deg) {
    int e = blockIdx.x * 256 + threadIdx.x;
    if (e < E) {
        int d = dst[e];
        if ((unsigned)d < (unsigned)Nn) atomicAdd(&deg[d], 1);
    }
}

__global__ __launch_bounds__(1024) void scan_deg(const int* __restrict__ deg, int N,
                                                 int* __restrict__ ofs) {
    __shared__ int part[1024];
    const int t = threadIdx.x;
    const int CH = (N + 1023) / 1024;
    const int base = t * CH;
    int s = 0;
    for (int i = 0; i < CH; ++i) { int idx = base + i; if (idx < N) s += deg[idx]; }
    part[t] = s;
    __syncthreads();
    for (int off = 1; off < 1024; off <<= 1) {
        int u = (t >= off) ? part[t - off] : 0;
        __syncthreads();
        part[t] += u;
        __syncthreads();
    }
    int run = (t == 0) ? 0 : part[t - 1];
    for (int i = 0; i < CH; ++i) {
        int idx = base + i;
        if (idx < N) { ofs[idx] = run; run += deg[idx]; }
    }
    if (t == 1023) ofs[N] = part[1023];
}

__global__ void fill_csr(const int* __restrict__ src, const int* __restrict__ dst, int E,
                         int Nn, const int* __restrict__ ofs, int* __restrict__ cursor,
                         int* __restrict__ esrc) {
    int e = blockIdx.x * 256 + threadIdx.x;
    if (e < E) {
        int d = dst[e];
        if ((unsigned)d < (unsigned)Nn) {
            int p = atomicAdd(&cursor[d], 1);
            esrc[ofs[d] + p] = src[e];
        }
    }
}

// ---------------- mean aggregation (X bf16 [*,512] -> G bf16 [*,512]) ----------------
__global__ __launch_bounds__(128) void agg_mean(const u16* __restrict__ X,
                                                const int* __restrict__ ofs,
                                                const int* __restrict__ esrc,
                                                u16* __restrict__ G, int Nn) {
    const int n = blockIdx.x;
    const int t = threadIdx.x;
    const int beg = ofs[n], end = ofs[n + 1];
    float a0 = 0.f, a1 = 0.f, a2 = 0.f, a3 = 0.f;
    for (int e = beg; e < end; ++e) {
        int s0 = esrc[e];
        if ((unsigned)s0 >= (unsigned)Nn) s0 = 0;  // safety clamp
        us4 v0 = *(const us4*)(X + (long)s0 * 512 + t * 4);
        a0 += b2f(v0[0]); a1 += b2f(v0[1]); a2 += b2f(v0[2]); a3 += b2f(v0[3]);
    }
    int d = end - beg;
    float inv = 1.0f / (float)(d > 1 ? d : 1);
    us4 o;
    o[0] = f2b(a0 * inv); o[1] = f2b(a1 * inv);
    o[2] = f2b(a2 * inv); o[3] = f2b(a3 * inv);
    *(us4*)(G + (long)n * 512 + t * 4) = o;
}

// ---------------- GEMM: C = [Aself|Aagg] @ Bt^T + bias ----------------
// A split at k=512, both halves [*,512] bf16. Bt [N,1024] bf16. K=1024 fixed.
// 128x128 tile, BK=32, 256 threads (4 waves 2x2), 16x16x32 bf16 MFMA.
__global__ __launch_bounds__(256) void gemm_split(
    const u16* __restrict__ Aself, const u16* __restrict__ Aagg,
    const u16* __restrict__ Bt, const u16* __restrict__ bias,
    void* __restrict__ Cv, int ldc, int Mstore, int do_relu,
    int out_mode, const int* __restrict__ flag) {
    __shared__ __align__(16) u16 lA[128 * 32];
    __shared__ __align__(16) u16 lB[128 * 32];
    const int tid = threadIdx.x;
    const int wv = tid >> 6;
    const int ln = tid & 63;
    const long brow = (long)blockIdx.x * 128;
    const int bcol = blockIdx.y * 128;
    const int wr = (wv >> 1) * 64;
    const int wc = (wv & 1) * 64;
    const int lrow = ln >> 2;       // 0..15
    const int lk = (ln & 3) * 8;    // 0,8,16,24
    const int m0 = ln & 15;
    const int kq = (ln >> 4) * 8;

    floatx4 acc[4][4];
#pragma unroll
    for (int i = 0; i < 4; ++i)
#pragma unroll
        for (int j = 0; j < 4; ++j) acc[i][j] = (floatx4){0.f, 0.f, 0.f, 0.f};

    for (int kt = 0; kt < 1024; kt += 32) {
        const u16* Ab = (kt < 512) ? Aself : Aagg;
        const int kc = kt & 511;
#pragma unroll
        for (int i = 0; i < 2; ++i) {
            const int c = i * 4 + wv;        // chunk 0..7 (16 rows each)
            const int row = c * 16 + lrow;
            GLOAD_LDS16(Ab + (brow + row) * 512 + kc + lk, lA + c * 512);
            GLOAD_LDS16(Bt + (long)(bcol + row) * 1024 + kt + lk, lB + c * 512);
        }
        __syncthreads();
        bf16x8 af[4], bf[4];
#pragma unroll
        for (int i = 0; i < 4; ++i)
            af[i] = *(const bf16x8*)(lA + (wr + i * 16 + m0) * 32 + kq);
#pragma unroll
        for (int j = 0; j < 4; ++j)
            bf[j] = *(const bf16x8*)(lB + (wc + j * 16 + m0) * 32 + kq);
#pragma unroll
        for (int i = 0; i < 4; ++i)
#pragma unroll
            for (int j = 0; j < 4; ++j)
                acc[i][j] = __builtin_amdgcn_mfma_f32_16x16x32_bf16(af[i], bf[j],
                                                                    acc[i][j], 0, 0, 0);
        __syncthreads();
    }

    float bv[4];
#pragma unroll
    for (int j = 0; j < 4; ++j) bv[j] = b2f(bias[bcol + wc + j * 16 + m0]);
    const int q4 = (ln >> 4) * 4;
    const int f32out = out_mode ? flag[0] : 0;
#pragma unroll
    for (int i = 0; i < 4; ++i) {
#pragma unroll
        for (int r = 0; r < 4; ++r) {
            long row = brow + wr + i * 16 + q4 + r;
            if (row < Mstore) {
#pragma unroll
                for (int j = 0; j < 4; ++j) {
                    float v = acc[i][j][r] + bv[j];
                    if (do_relu) v = fmaxf(v, 0.0f);
                    long idx = row * (long)ldc + (bcol + wc + j * 16 + m0);
                    if (f32out) ((float*)Cv)[idx] = v;
                    else        ((u16*)Cv)[idx] = f2b(v);
                }
            }
        }
    }
}

// ---------------- launch ----------------
extern "C" void kernel_launch(void* const* d_in, const int* in_sizes, int n_in,
                              void* d_out, int out_size, void* d_ws, size_t ws_size,
                              hipStream_t stream) {
    const int D = 512, NCLS = 128, K = 1024;
    const int Nn = in_sizes[0] / D;          // 10000
    const int E  = in_sizes[5];              // 160000
    const int mtiles = (Nn + 127) / 128;     // 79
    const int Mpad = mtiles * 128;           // 10112

    const int* src = (const int*)d_in[5];
    const int* dst = (const int*)d_in[6];

    char* p = (char*)d_ws;
    u16* Hb  = (u16*)p; p += (size_t)Mpad * D * 2;    // h as bf16
    u16* h1  = (u16*)p; p += (size_t)Mpad * D * 2;    // relu layer-1 out
    u16* G   = (u16*)p; p += (size_t)Mpad * D * 2;    // aggregated means
    u16* W1t = (u16*)p; p += (size_t)D * K * 2;
    u16* W2t = (u16*)p; p += (size_t)NCLS * K * 2;
    u16* b1c = (u16*)p; p += 1024;
    u16* b2c = (u16*)p; p += 1024;
    int* flags  = (int*)p; p += 256;
    int* deg    = (int*)p; p += (size_t)(Nn + 64) * 4;
    int* cursor = (int*)p; p += (size_t)(Nn + 64) * 4;
    int* ofs    = (int*)p; p += (size_t)(Nn + 64) * 4;
    int* esrc   = (int*)p; p += (size_t)E * 4;

    // zero degree + cursor (contiguous)
    hipMemsetAsync(deg, 0, (size_t)(Nn + 64) * 4 * 2, stream);

    detect_f32<<<5, 1024, 0, stream>>>(
        (const u16*)d_in[0], (const u16*)d_in[1], (const u16*)d_in[2],
        (const u16*)d_in[3], (const u16*)d_in[4],
        in_sizes[0], in_sizes[1], in_sizes[2], in_sizes[3], in_sizes[4], flags);

    cvt_to_bf16<<<(Nn * D / 8 + 255) / 256, 256, 0, stream>>>(d_in[0], flags + 0, Hb, Nn * D);
    cvt_wt<<<dim3(D / 32, K / 32), 256, 0, stream>>>(d_in[1], flags + 1, W1t, K, D);
    cvt_to_bf16<<<1, 256, 0, stream>>>(d_in[2], flags + 2, b1c, D);
    cvt_wt<<<dim3(NCLS / 32, K / 32), 256, 0, stream>>>(d_in[3], flags + 3, W2t, K, NCLS);
    cvt_to_bf16<<<1, 256, 0, stream>>>(d_in[4], flags + 4, b2c, NCLS);

    count_deg<<<(E + 255) / 256, 256, 0, stream>>>(dst, E, Nn, deg);
    scan_deg<<<1, 1024, 0, stream>>>(deg, Nn, ofs);
    fill_csr<<<(E + 255) / 256, 256, 0, stream>>>(src, dst, E, Nn, ofs, cursor, esrc);

    // layer 1
    agg_mean<<<Nn, 128, 0, stream>>>(Hb, ofs, esrc, G, Nn);
    gemm_split<<<dim3(mtiles, D / 128), 256, 0, stream>>>(Hb, G, W1t, b1c,
                                                          h1, D, Nn, 1, 0, flags);
    // layer 2
    agg_mean<<<Nn, 128, 0, stream>>>(h1, ofs, esrc, G, Nn);
    gemm_split<<<dim3(mtiles, NCLS / 128), 256, 0, stream>>>(h1, G, W2t, b2c,
                                                             d_out, NCLS, Nn, 0, 1, flags);
}

// Round 3
// 228.458 us; speedup vs baseline: 2.8439x; 2.8439x over previous
//
#include <hip/hip_runtime.h>

typedef unsigned short u16;
typedef __attribute__((ext_vector_type(4))) float floatx4;
typedef __attribute__((ext_vector_type(8))) __bf16 bf16x8;
typedef __attribute__((ext_vector_type(4))) unsigned short us4;
typedef __attribute__((ext_vector_type(8))) unsigned short us8;

static __device__ __forceinline__ float b2f(u16 v) {
    union { unsigned u; float f; } x; x.u = ((unsigned)v) << 16; return x.f;
}
static __device__ __forceinline__ u16 f2b(float f) {
    union { float f; unsigned u; } x; x.f = f;
    unsigned u = x.u;
    return (u16)((u + 0x7fffu + ((u >> 16) & 1u)) >> 16);
}

#define GLOAD_LDS16(g, l) __builtin_amdgcn_global_load_lds( \
    (const __attribute__((address_space(1))) void*)(g),     \
    (__attribute__((address_space(3))) void*)(l), 16, 0, 0)

// ---------------- dtype detection (sampled) ----------------
// Even u16 halves of a float32 array are ~uniform random bits; as bf16 each
// sample has ~50% chance of |x|>=1.0. 256 samples/tensor -> P(miss) ~ 2^-256.
// bf16 tensors in this problem have all |values| < ~6 (never >=1.0 at the
// sampled LOW half?  For bf16 data p[2j] IS element 2j; values |x|<6 can
// exceed 1.0!  -> use threshold 64.0 instead: normal(0,1)*concat data never
// reaches 64, while fp32 mantissa-garbage exceeds 64 with prob ~0.44/sample.
// 256 samples -> P(miss) ~ (1-0.44)^256 ~ 1e-64. Still impossible.
__global__ __launch_bounds__(256) void detect_f32(
    const u16* p0, const u16* p1, const u16* p2, const u16* p3, const u16* p4,
    int n0, int n1, int n2, int n3, int n4, int* __restrict__ flags) {
    const u16* P[5] = {p0, p1, p2, p3, p4};
    const int N[5] = {n0, n1, n2, n3, n4};
    __shared__ int any[5];
    if (threadIdx.x < 5) any[threadIdx.x] = 0;
    __syncthreads();
    for (int b = 0; b < 5; ++b) {
        const u16* p = P[b];
        const int lim = N[b] < 512 ? N[b] : 512;  // u16 index bound = min(n,512)
        int found = 0;
        for (int j = threadIdx.x; 2 * j < lim; j += 256) {
            unsigned v = p[2 * j] & 0x7fffu;
            if (v >= 0x4280u) found = 1;  // |bf16| >= 64.0 (incl inf/nan)
        }
        if (found) atomicOr(&any[b], 1);
    }
    __syncthreads();
    if (threadIdx.x < 5) flags[threadIdx.x] = any[threadIdx.x];
}

// ---------------- convert to internal bf16 ----------------
__global__ __launch_bounds__(256) void cvt_to_bf16(const void* __restrict__ src,
                                                   const int* __restrict__ flag,
                                                   u16* __restrict__ dstp, int nelem) {
    int i = (blockIdx.x * 256 + threadIdx.x) * 8;
    if (i >= nelem) return;
    if (*flag) {
        const float* s = (const float*)src;
        us8 o;
#pragma unroll
        for (int k = 0; k < 8; ++k) o[k] = f2b(s[i + k]);
        *(us8*)(dstp + i) = o;
    } else {
        *(us8*)(dstp + i) = *(const us8*)((const u16*)src + i);
    }
}

// W [K,N] row-major (fp32 or bf16) -> Wt [N,K] bf16. K,N multiples of 32.
__global__ __launch_bounds__(256) void cvt_wt(const void* __restrict__ W,
                                              const int* __restrict__ flag,
                                              u16* __restrict__ Wt, int K, int N) {
    __shared__ u16 tile[32][33];
    const int bx = blockIdx.x * 32;  // n
    const int by = blockIdx.y * 32;  // k
    const int tx = threadIdx.x & 31, ty = threadIdx.x >> 5;
    const int f = *flag;
    for (int i = ty; i < 32; i += 8) {
        long idx = (long)(by + i) * N + (bx + tx);
        tile[i][tx] = f ? f2b(((const float*)W)[idx]) : ((const u16*)W)[idx];
    }
    __syncthreads();
    for (int i = ty; i < 32; i += 8)
        Wt[(long)(bx + i) * K + (by + tx)] = tile[tx][i];
}

// ---------------- CSR build ----------------
__global__ void count_deg(const int* __restrict__ dst, int E, int Nn,
                          int* __restrict__ deg) {
    int e = blockIdx.x * 256 + threadIdx.x;
    if (e < E) {
        int d = dst[e];
        if ((unsigned)d < (unsigned)Nn) atomicAdd(&deg[d], 1);
    }
}

__global__ __launch_bounds__(1024) void scan_deg(const int* __restrict__ deg, int N,
                                                 int* __restrict__ ofs) {
    __shared__ int part[1024];
    const int t = threadIdx.x;
    const int CH = (N + 1023) / 1024;
    const int base = t * CH;
    int s = 0;
    for (int i = 0; i < CH; ++i) { int idx = base + i; if (idx < N) s += deg[idx]; }
    part[t] = s;
    __syncthreads();
    for (int off = 1; off < 1024; off <<= 1) {
        int u = (t >= off) ? part[t - off] : 0;
        __syncthreads();
        part[t] += u;
        __syncthreads();
    }
    int run = (t == 0) ? 0 : part[t - 1];
    for (int i = 0; i < CH; ++i) {
        int idx = base + i;
        if (idx < N) { ofs[idx] = run; run += deg[idx]; }
    }
    if (t == 1023) ofs[N] = part[1023];
}

__global__ void fill_csr(const int* __restrict__ src, const int* __restrict__ dst, int E,
                         int Nn, const int* __restrict__ ofs, int* __restrict__ cursor,
                         int* __restrict__ esrc) {
    int e = blockIdx.x * 256 + threadIdx.x;
    if (e < E) {
        int d = dst[e];
        if ((unsigned)d < (unsigned)Nn) {
            int p = atomicAdd(&cursor[d], 1);
            esrc[ofs[d] + p] = src[e];
        }
    }
}

// ---------------- mean aggregation (X bf16 [*,512] -> G bf16 [*,512]) ----------------
__global__ __launch_bounds__(128) void agg_mean(const u16* __restrict__ X,
                                                const int* __restrict__ ofs,
                                                const int* __restrict__ esrc,
                                                u16* __restrict__ G, int Nn) {
    const int n = blockIdx.x;
    const int t = threadIdx.x;
    const int beg = ofs[n], end = ofs[n + 1];
    float a0 = 0.f, a1 = 0.f, a2 = 0.f, a3 = 0.f;
    for (int e = beg; e < end; ++e) {
        int s0 = esrc[e];
        if ((unsigned)s0 >= (unsigned)Nn) s0 = 0;  // safety clamp
        us4 v0 = *(const us4*)(X + (long)s0 * 512 + t * 4);
        a0 += b2f(v0[0]); a1 += b2f(v0[1]); a2 += b2f(v0[2]); a3 += b2f(v0[3]);
    }
    int d = end - beg;
    float inv = 1.0f / (float)(d > 1 ? d : 1);
    us4 o;
    o[0] = f2b(a0 * inv); o[1] = f2b(a1 * inv);
    o[2] = f2b(a2 * inv); o[3] = f2b(a3 * inv);
    *(us4*)(G + (long)n * 512 + t * 4) = o;
}

// ---------------- GEMM: C = [Aself|Aagg] @ Bt^T + bias ----------------
// A split at k=512, both halves [*,512] bf16. Bt [N,1024] bf16. K=1024 fixed.
// 128x128 tile, BK=32, 256 threads (4 waves 2x2), 16x16x32 bf16 MFMA.
__global__ __launch_bounds__(256) void gemm_split(
    const u16* __restrict__ Aself, const u16* __restrict__ Aagg,
    const u16* __restrict__ Bt, const u16* __restrict__ bias,
    void* __restrict__ Cv, int ldc, int Mstore, int do_relu,
    int out_mode, const int* __restrict__ flag) {
    __shared__ __align__(16) u16 lA[128 * 32];
    __shared__ __align__(16) u16 lB[128 * 32];
    const int tid = threadIdx.x;
    const int wv = tid >> 6;
    const int ln = tid & 63;
    const long brow = (long)blockIdx.x * 128;
    const int bcol = blockIdx.y * 128;
    const int wr = (wv >> 1) * 64;
    const int wc = (wv & 1) * 64;
    const int lrow = ln >> 2;       // 0..15
    const int lk = (ln & 3) * 8;    // 0,8,16,24
    const int m0 = ln & 15;
    const int kq = (ln >> 4) * 8;

    floatx4 acc[4][4];
#pragma unroll
    for (int i = 0; i < 4; ++i)
#pragma unroll
        for (int j = 0; j < 4; ++j) acc[i][j] = (floatx4){0.f, 0.f, 0.f, 0.f};

    for (int kt = 0; kt < 1024; kt += 32) {
        const u16* Ab = (kt < 512) ? Aself : Aagg;
        const int kc = kt & 511;
#pragma unroll
        for (int i = 0; i < 2; ++i) {
            const int c = i * 4 + wv;        // chunk 0..7 (16 rows each)
            const int row = c * 16 + lrow;
            GLOAD_LDS16(Ab + (brow + row) * 512 + kc + lk, lA + c * 512);
            GLOAD_LDS16(Bt + (long)(bcol + row) * 1024 + kt + lk, lB + c * 512);
        }
        __syncthreads();
        bf16x8 af[4], bf[4];
#pragma unroll
        for (int i = 0; i < 4; ++i)
            af[i] = *(const bf16x8*)(lA + (wr + i * 16 + m0) * 32 + kq);
#pragma unroll
        for (int j = 0; j < 4; ++j)
            bf[j] = *(const bf16x8*)(lB + (wc + j * 16 + m0) * 32 + kq);
#pragma unroll
        for (int i = 0; i < 4; ++i)
#pragma unroll
            for (int j = 0; j < 4; ++j)
                acc[i][j] = __builtin_amdgcn_mfma_f32_16x16x32_bf16(af[i], bf[j],
                                                                    acc[i][j], 0, 0, 0);
        __syncthreads();
    }

    float bv[4];
#pragma unroll
    for (int j = 0; j < 4; ++j) bv[j] = b2f(bias[bcol + wc + j * 16 + m0]);
    const int q4 = (ln >> 4) * 4;
    const int f32out = out_mode ? flag[0] : 0;
#pragma unroll
    for (int i = 0; i < 4; ++i) {
#pragma unroll
        for (int r = 0; r < 4; ++r) {
            long row = brow + wr + i * 16 + q4 + r;
            if (row < Mstore) {
#pragma unroll
                for (int j = 0; j < 4; ++j) {
                    float v = acc[i][j][r] + bv[j];
                    if (do_relu) v = fmaxf(v, 0.0f);
                    long idx = row * (long)ldc + (bcol + wc + j * 16 + m0);
                    if (f32out) ((float*)Cv)[idx] = v;
                    else        ((u16*)Cv)[idx] = f2b(v);
                }
            }
        }
    }
}

// ---------------- launch ----------------
extern "C" void kernel_launch(void* const* d_in, const int* in_sizes, int n_in,
                              void* d_out, int out_size, void* d_ws, size_t ws_size,
                              hipStream_t stream) {
    const int D = 512, NCLS = 128, K = 1024;
    const int Nn = in_sizes[0] / D;          // 10000
    const int E  = in_sizes[5];              // 160000
    const int mtiles = (Nn + 127) / 128;     // 79
    const int Mpad = mtiles * 128;           // 10112

    const int* src = (const int*)d_in[5];
    const int* dst = (const int*)d_in[6];

    char* p = (char*)d_ws;
    u16* Hb  = (u16*)p; p += (size_t)Mpad * D * 2;    // h as bf16
    u16* h1  = (u16*)p; p += (size_t)Mpad * D * 2;    // relu layer-1 out
    u16* G   = (u16*)p; p += (size_t)Mpad * D * 2;    // aggregated means
    u16* W1t = (u16*)p; p += (size_t)D * K * 2;
    u16* W2t = (u16*)p; p += (size_t)NCLS * K * 2;
    u16* b1c = (u16*)p; p += 1024;
    u16* b2c = (u16*)p; p += 1024;
    int* flags  = (int*)p; p += 256;
    int* deg    = (int*)p; p += (size_t)(Nn + 64) * 4;
    int* cursor = (int*)p; p += (size_t)(Nn + 64) * 4;
    int* ofs    = (int*)p; p += (size_t)(Nn + 64) * 4;
    int* esrc   = (int*)p; p += (size_t)E * 4;

    // zero degree + cursor (contiguous)
    hipMemsetAsync(deg, 0, (size_t)(Nn + 64) * 4 * 2, stream);

    detect_f32<<<1, 256, 0, stream>>>(
        (const u16*)d_in[0], (const u16*)d_in[1], (const u16*)d_in[2],
        (const u16*)d_in[3], (const u16*)d_in[4],
        in_sizes[0], in_sizes[1], in_sizes[2], in_sizes[3], in_sizes[4], flags);

    cvt_to_bf16<<<(Nn * D / 8 + 255) / 256, 256, 0, stream>>>(d_in[0], flags + 0, Hb, Nn * D);
    cvt_wt<<<dim3(D / 32, K / 32), 256, 0, stream>>>(d_in[1], flags + 1, W1t, K, D);
    cvt_to_bf16<<<1, 256, 0, stream>>>(d_in[2], flags + 2, b1c, D);
    cvt_wt<<<dim3(NCLS / 32, K / 32), 256, 0, stream>>>(d_in[3], flags + 3, W2t, K, NCLS);
    cvt_to_bf16<<<1, 256, 0, stream>>>(d_in[4], flags + 4, b2c, NCLS);

    count_deg<<<(E + 255) / 256, 256, 0, stream>>>(dst, E, Nn, deg);
    scan_deg<<<1, 1024, 0, stream>>>(deg, Nn, ofs);
    fill_csr<<<(E + 255) / 256, 256, 0, stream>>>(src, dst, E, Nn, ofs, cursor, esrc);

    // layer 1
    agg_mean<<<Nn, 128, 0, stream>>>(Hb, ofs, esrc, G, Nn);
    gemm_split<<<dim3(mtiles, D / 128), 256, 0, stream>>>(Hb, G, W1t, b1c,
                                                          h1, D, Nn, 1, 0, flags);
    // layer 2
    agg_mean<<<Nn, 128, 0, stream>>>(h1, ofs, esrc, G, Nn);
    gemm_split<<<dim3(mtiles, NCLS / 128), 256, 0, stream>>>(h1, G, W2t, b2c,
                                                             d_out, NCLS, Nn, 0, 1, flags);
}

// Round 4
// 205.271 us; speedup vs baseline: 3.1651x; 1.1130x over previous
//
#include <hip/hip_runtime.h>

typedef unsigned short u16;
typedef __attribute__((ext_vector_type(4))) float floatx4;
typedef __attribute__((ext_vector_type(8))) __bf16 bf16x8;
typedef __attribute__((ext_vector_type(2))) unsigned short us2;
typedef __attribute__((ext_vector_type(4))) unsigned short us4;
typedef __attribute__((ext_vector_type(8))) unsigned short us8;

static __device__ __forceinline__ float b2f(u16 v) {
    union { unsigned u; float f; } x; x.u = ((unsigned)v) << 16; return x.f;
}
static __device__ __forceinline__ u16 f2b(float f) {
    union { float f; unsigned u; } x; x.f = f;
    unsigned u = x.u;
    return (u16)((u + 0x7fffu + ((u >> 16) & 1u)) >> 16);
}

#define GLOAD_LDS16(g, l) __builtin_amdgcn_global_load_lds( \
    (const __attribute__((address_space(1))) void*)(g),     \
    (__attribute__((address_space(3))) void*)(l), 16, 0, 0)

// ---------------- dtype detection (sampled, ~4KB/tensor) ----------------
__global__ __launch_bounds__(256) void detect_f32(
    const u16* p0, const u16* p1, const u16* p2, const u16* p3, const u16* p4,
    int n0, int n1, int n2, int n3, int n4, int* __restrict__ flags) {
    const u16* P[5] = {p0, p1, p2, p3, p4};
    const int N[5] = {n0, n1, n2, n3, n4};
    __shared__ int any[5];
    if (threadIdx.x < 5) any[threadIdx.x] = 0;
    __syncthreads();
    for (int b = 0; b < 5; ++b) {
        const u16* p = P[b];
        const int lim = N[b] < 512 ? N[b] : 512;
        int found = 0;
        for (int j = threadIdx.x; 2 * j < lim; j += 256) {
            unsigned v = p[2 * j] & 0x7fffu;
            if (v >= 0x4280u) found = 1;  // |bf16(bits)| >= 64.0
        }
        if (found) atomicOr(&any[b], 1);
    }
    __syncthreads();
    if (threadIdx.x < 5) flags[threadIdx.x] = any[threadIdx.x];
}

// ---------------- convert to internal bf16 ----------------
__global__ __launch_bounds__(256) void cvt_to_bf16(const void* __restrict__ src,
                                                   const int* __restrict__ flag,
                                                   u16* __restrict__ dstp, int nelem) {
    int i = (blockIdx.x * 256 + threadIdx.x) * 8;
    if (i >= nelem) return;
    if (*flag) {
        const float* s = (const float*)src;
        us8 o;
#pragma unroll
        for (int k = 0; k < 8; ++k) o[k] = f2b(s[i + k]);
        *(us8*)(dstp + i) = o;
    } else {
        *(us8*)(dstp + i) = *(const us8*)((const u16*)src + i);
    }
}

// W rows [koff, koff+512) x cols [0,Nw) -> Wt[(noff+n)*512 + k] (bf16)
// grid (Nw/32, 512/32), 256 threads
__global__ __launch_bounds__(256) void cvt_wt(const void* __restrict__ W,
                                              const int* __restrict__ flag,
                                              u16* __restrict__ Wt,
                                              int Nw, int koff, int noff) {
    __shared__ u16 tile[32][33];
    const int bx = blockIdx.x * 32;  // n
    const int by = blockIdx.y * 32;  // k
    const int tx = threadIdx.x & 31, ty = threadIdx.x >> 5;
    const int f = *flag;
    for (int i = ty; i < 32; i += 8) {
        long idx = (long)(koff + by + i) * Nw + (bx + tx);
        tile[i][tx] = f ? f2b(((const float*)W)[idx]) : ((const u16*)W)[idx];
    }
    __syncthreads();
    for (int i = ty; i < 32; i += 8)
        Wt[(long)(noff + bx + i) * 512 + (by + tx)] = tile[tx][i];
}

// ---------------- CSR build ----------------
__global__ void count_deg(const int* __restrict__ dst, int E, int Nn,
                          int* __restrict__ deg) {
    int e = blockIdx.x * 256 + threadIdx.x;
    if (e < E) {
        int d = dst[e];
        if ((unsigned)d < (unsigned)Nn) atomicAdd(&deg[d], 1);
    }
}

__global__ __launch_bounds__(1024) void scan_deg(const int* __restrict__ deg, int N,
                                                 int* __restrict__ ofs) {
    __shared__ int part[1024];
    const int t = threadIdx.x;
    const int CH = (N + 1023) / 1024;
    const int base = t * CH;
    int s = 0;
    for (int i = 0; i < CH; ++i) { int idx = base + i; if (idx < N) s += deg[idx]; }
    part[t] = s;
    __syncthreads();
    for (int off = 1; off < 1024; off <<= 1) {
        int u = (t >= off) ? part[t - off] : 0;
        __syncthreads();
        part[t] += u;
        __syncthreads();
    }
    int run = (t == 0) ? 0 : part[t - 1];
    for (int i = 0; i < CH; ++i) {
        int idx = base + i;
        if (idx < N) { ofs[idx] = run; run += deg[idx]; }
    }
    if (t == 1023) ofs[N] = part[1023];
}

__global__ void fill_csr(const int* __restrict__ src, const int* __restrict__ dst, int E,
                         int Nn, const int* __restrict__ ofs, int* __restrict__ cursor,
                         int* __restrict__ esrc) {
    int e = blockIdx.x * 256 + threadIdx.x;
    if (e < E) {
        int d = dst[e];
        if ((unsigned)d < (unsigned)Nn) {
            int p = atomicAdd(&cursor[d], 1);
            esrc[ofs[d] + p] = src[e];
        }
    }
}

// ---------------- fused layer-1 tail: h1 = relu(C1s + mean(P1[nbrs]) + b1) ----------------
// block = 128 threads = one node; 4 cols/thread (width 512)
__global__ __launch_bounds__(128) void agg_h1(const u16* __restrict__ P1,
                                              const u16* __restrict__ C1s,
                                              const u16* __restrict__ b1c,
                                              const int* __restrict__ ofs,
                                              const int* __restrict__ esrc,
                                              u16* __restrict__ h1, int Nn) {
    const int n = blockIdx.x;
    const int t = threadIdx.x;
    const int beg = ofs[n], end = ofs[n + 1];
    float a0 = 0.f, a1 = 0.f, a2 = 0.f, a3 = 0.f;
    int e = beg;
    for (; e + 1 < end; e += 2) {
        int s0 = esrc[e], s1 = esrc[e + 1];
        if ((unsigned)s0 >= (unsigned)Nn) s0 = 0;
        if ((unsigned)s1 >= (unsigned)Nn) s1 = 0;
        us4 v0 = *(const us4*)(P1 + (long)s0 * 512 + t * 4);
        us4 v1 = *(const us4*)(P1 + (long)s1 * 512 + t * 4);
        a0 += b2f(v0[0]) + b2f(v1[0]);
        a1 += b2f(v0[1]) + b2f(v1[1]);
        a2 += b2f(v0[2]) + b2f(v1[2]);
        a3 += b2f(v0[3]) + b2f(v1[3]);
    }
    if (e < end) {
        int s0 = esrc[e];
        if ((unsigned)s0 >= (unsigned)Nn) s0 = 0;
        us4 v0 = *(const us4*)(P1 + (long)s0 * 512 + t * 4);
        a0 += b2f(v0[0]); a1 += b2f(v0[1]); a2 += b2f(v0[2]); a3 += b2f(v0[3]);
    }
    int d = end - beg;
    float inv = 1.0f / (float)(d > 1 ? d : 1);
    us4 sf = *(const us4*)(C1s + (long)n * 512 + t * 4);
    us4 bv = *(const us4*)(b1c + t * 4);
    us4 o;
    o[0] = f2b(fmaxf(b2f(sf[0]) + a0 * inv + b2f(bv[0]), 0.f));
    o[1] = f2b(fmaxf(b2f(sf[1]) + a1 * inv + b2f(bv[1]), 0.f));
    o[2] = f2b(fmaxf(b2f(sf[2]) + a2 * inv + b2f(bv[2]), 0.f));
    o[3] = f2b(fmaxf(b2f(sf[3]) + a3 * inv + b2f(bv[3]), 0.f));
    *(us4*)(h1 + (long)n * 512 + t * 4) = o;
}

// ---------------- fused layer-2 tail: out = C2s + mean(P2[nbrs]) + b2 ----------------
// block = 256 threads = 4 waves = 4 nodes; lane handles 2 cols (width 128)
__global__ __launch_bounds__(256) void agg_out(const u16* __restrict__ P2,
                                               const u16* __restrict__ C2s,
                                               const u16* __restrict__ b2c,
                                               const int* __restrict__ ofs,
                                               const int* __restrict__ esrc,
                                               void* __restrict__ outv, int Nn,
                                               const int* __restrict__ flag) {
    const int n = blockIdx.x * 4 + (threadIdx.x >> 6);
    const int l = threadIdx.x & 63;
    if (n >= Nn) return;
    const int beg = ofs[n], end = ofs[n + 1];
    float a0 = 0.f, a1 = 0.f;
    int e = beg;
    for (; e + 1 < end; e += 2) {
        int s0 = esrc[e], s1 = esrc[e + 1];
        if ((unsigned)s0 >= (unsigned)Nn) s0 = 0;
        if ((unsigned)s1 >= (unsigned)Nn) s1 = 0;
        us2 v0 = *(const us2*)(P2 + (long)s0 * 128 + l * 2);
        us2 v1 = *(const us2*)(P2 + (long)s1 * 128 + l * 2);
        a0 += b2f(v0[0]) + b2f(v1[0]);
        a1 += b2f(v0[1]) + b2f(v1[1]);
    }
    if (e < end) {
        int s0 = esrc[e];
        if ((unsigned)s0 >= (unsigned)Nn) s0 = 0;
        us2 v0 = *(const us2*)(P2 + (long)s0 * 128 + l * 2);
        a0 += b2f(v0[0]); a1 += b2f(v0[1]);
    }
    int d = end - beg;
    float inv = 1.0f / (float)(d > 1 ? d : 1);
    us2 sf = *(const us2*)(C2s + (long)n * 128 + l * 2);
    us2 bv = *(const us2*)(b2c + l * 2);
    float o0 = b2f(sf[0]) + a0 * inv + b2f(bv[0]);
    float o1 = b2f(sf[1]) + a1 * inv + b2f(bv[1]);
    if (*flag) {
        float* o = (float*)outv + (long)n * 128 + l * 2;
        o[0] = o0; o[1] = o1;
    } else {
        us2 ob; ob[0] = f2b(o0); ob[1] = f2b(o1);
        *(us2*)((u16*)outv + (long)n * 128 + l * 2) = ob;
    }
}

// ---------------- GEMM: [C0|C1] = A[M,512] @ Bt[N,512]^T (bf16 out) ----------------
// 128x128 tile, BK=32, 256 threads (4 waves 2x2), 16x16x32 bf16 MFMA.
// Columns < Nsplit -> C0 (ld0), else -> C1 (ld1). Nsplit multiple of 128.
__global__ __launch_bounds__(256) void gemm_split(
    const u16* __restrict__ A, const u16* __restrict__ Bt,
    u16* __restrict__ C0, int ld0, u16* __restrict__ C1, int ld1,
    int Nsplit, int Mstore) {
    __shared__ __align__(16) u16 lA[128 * 32];
    __shared__ __align__(16) u16 lB[128 * 32];
    const int tid = threadIdx.x;
    const int wv = tid >> 6;
    const int ln = tid & 63;
    const long brow = (long)blockIdx.x * 128;
    const int bcol = blockIdx.y * 128;
    const int wr = (wv >> 1) * 64;
    const int wc = (wv & 1) * 64;
    const int lrow = ln >> 2;       // 0..15
    const int lk = (ln & 3) * 8;    // 0,8,16,24
    const int m0 = ln & 15;
    const int kq = (ln >> 4) * 8;

    floatx4 acc[4][4];
#pragma unroll
    for (int i = 0; i < 4; ++i)
#pragma unroll
        for (int j = 0; j < 4; ++j) acc[i][j] = (floatx4){0.f, 0.f, 0.f, 0.f};

    for (int kt = 0; kt < 512; kt += 32) {
#pragma unroll
        for (int i = 0; i < 2; ++i) {
            const int c = i * 4 + wv;        // chunk 0..7 (16 rows each)
            const int row = c * 16 + lrow;
            GLOAD_LDS16(A + (brow + row) * 512 + kt + lk, lA + c * 512);
            GLOAD_LDS16(Bt + (long)(bcol + row) * 512 + kt + lk, lB + c * 512);
        }
        __syncthreads();
        bf16x8 af[4], bf[4];
#pragma unroll
        for (int i = 0; i < 4; ++i)
            af[i] = *(const bf16x8*)(lA + (wr + i * 16 + m0) * 32 + kq);
#pragma unroll
        for (int j = 0; j < 4; ++j)
            bf[j] = *(const bf16x8*)(lB + (wc + j * 16 + m0) * 32 + kq);
#pragma unroll
        for (int i = 0; i < 4; ++i)
#pragma unroll
            for (int j = 0; j < 4; ++j)
                acc[i][j] = __builtin_amdgcn_mfma_f32_16x16x32_bf16(af[i], bf[j],
                                                                    acc[i][j], 0, 0, 0);
        __syncthreads();
    }

    u16* C = (bcol < Nsplit) ? C0 : C1;
    const int ldc = (bcol < Nsplit) ? ld0 : ld1;
    const int coff = (bcol < Nsplit) ? bcol : bcol - Nsplit;
    const int q4 = (ln >> 4) * 4;
#pragma unroll
    for (int i = 0; i < 4; ++i) {
#pragma unroll
        for (int r = 0; r < 4; ++r) {
            long row = brow + wr + i * 16 + q4 + r;
            if (row < Mstore) {
#pragma unroll
                for (int j = 0; j < 4; ++j)
                    C[row * (long)ldc + (coff + wc + j * 16 + m0)] = f2b(acc[i][j][r]);
            }
        }
    }
}

// ---------------- launch ----------------
extern "C" void kernel_launch(void* const* d_in, const int* in_sizes, int n_in,
                              void* d_out, int out_size, void* d_ws, size_t ws_size,
                              hipStream_t stream) {
    const int D = 512, NCLS = 128;
    const int Nn = in_sizes[0] / D;          // 10000
    const int E  = in_sizes[5];              // 160000
    const int mtiles = (Nn + 127) / 128;     // 79
    const int Mpad = mtiles * 128;           // 10112

    const int* src = (const int*)d_in[5];
    const int* dst = (const int*)d_in[6];

    char* p = (char*)d_ws;
    u16* Hb  = (u16*)p; p += (size_t)Mpad * D * 2;     // h as bf16
    u16* h1  = (u16*)p; p += (size_t)Mpad * D * 2;     // layer-1 activations
    u16* C1s = (u16*)p; p += (size_t)Mpad * D * 2;     // h @ W1_self
    u16* P1  = (u16*)p; p += (size_t)Mpad * D * 2;     // h @ W1_agg
    u16* C2s = (u16*)p; p += (size_t)Mpad * NCLS * 2;  // h1 @ W2_self
    u16* P2  = (u16*)p; p += (size_t)Mpad * NCLS * 2;  // h1 @ W2_agg
    u16* W1T = (u16*)p; p += (size_t)1024 * D * 2;     // [W1s|W1a] transposed, ld 512
    u16* W2T = (u16*)p; p += (size_t)256 * D * 2;      // [W2s|W2a] transposed, ld 512
    u16* b1c = (u16*)p; p += 1024;
    u16* b2c = (u16*)p; p += 1024;
    int* flags  = (int*)p; p += 256;
    int* deg    = (int*)p; p += (size_t)(Nn + 64) * 4;
    int* cursor = (int*)p; p += (size_t)(Nn + 64) * 4;
    int* ofs    = (int*)p; p += (size_t)(Nn + 64) * 4;
    int* esrc   = (int*)p; p += (size_t)E * 4;

    hipMemsetAsync(deg, 0, (size_t)(Nn + 64) * 4 * 2, stream);

    detect_f32<<<1, 256, 0, stream>>>(
        (const u16*)d_in[0], (const u16*)d_in[1], (const u16*)d_in[2],
        (const u16*)d_in[3], (const u16*)d_in[4],
        in_sizes[0], in_sizes[1], in_sizes[2], in_sizes[3], in_sizes[4], flags);

    cvt_to_bf16<<<(Nn * D / 8 + 255) / 256, 256, 0, stream>>>(d_in[0], flags + 0, Hb, Nn * D);
    // W1 [1024,512]: rows 0..511 -> W1T rows 0..511 (self), rows 512..1023 -> 512..1023 (agg)
    cvt_wt<<<dim3(D / 32, 16), 256, 0, stream>>>(d_in[1], flags + 1, W1T, D, 0, 0);
    cvt_wt<<<dim3(D / 32, 16), 256, 0, stream>>>(d_in[1], flags + 1, W1T, D, 512, 512);
    cvt_to_bf16<<<1, 256, 0, stream>>>(d_in[2], flags + 2, b1c, D);
    // W2 [1024,128]: rows 0..511 -> W2T rows 0..127 (self), rows 512..1023 -> 128..255 (agg)
    cvt_wt<<<dim3(NCLS / 32, 16), 256, 0, stream>>>(d_in[3], flags + 3, W2T, NCLS, 0, 0);
    cvt_wt<<<dim3(NCLS / 32, 16), 256, 0, stream>>>(d_in[3], flags + 3, W2T, NCLS, 512, 128);
    cvt_to_bf16<<<1, 256, 0, stream>>>(d_in[4], flags + 4, b2c, NCLS);

    count_deg<<<(E + 255) / 256, 256, 0, stream>>>(dst, E, Nn, deg);
    scan_deg<<<1, 1024, 0, stream>>>(deg, Nn, ofs);
    fill_csr<<<(E + 255) / 256, 256, 0, stream>>>(src, dst, E, Nn, ofs, cursor, esrc);

    // layer 1: [C1s|P1] = Hb @ W1T^T ; h1 = relu(C1s + mean(P1[nbrs]) + b1)
    gemm_split<<<dim3(mtiles, 8), 256, 0, stream>>>(Hb, W1T, C1s, D, P1, D, D, Nn);
    agg_h1<<<Nn, 128, 0, stream>>>(P1, C1s, b1c, ofs, esrc, h1, Nn);

    // layer 2: [C2s|P2] = h1 @ W2T^T ; out = C2s + mean(P2[nbrs]) + b2
    gemm_split<<<dim3(mtiles, 2), 256, 0, stream>>>(h1, W2T, C2s, NCLS, P2, NCLS, NCLS, Nn);
    agg_out<<<(Nn + 3) / 4, 256, 0, stream>>>(P2, C2s, b2c, ofs, esrc, d_out, Nn, flags);
}

// Round 5
// 188.839 us; speedup vs baseline: 3.4405x; 1.0870x over previous
//
#include <hip/hip_runtime.h>

typedef unsigned short u16;
typedef __attribute__((ext_vector_type(4))) float floatx4;
typedef __attribute__((ext_vector_type(8))) __bf16 bf16x8;
typedef __attribute__((ext_vector_type(2))) unsigned short us2;
typedef __attribute__((ext_vector_type(4))) unsigned short us4;
typedef __attribute__((ext_vector_type(8))) unsigned short us8;

static __device__ __forceinline__ float b2f(u16 v) {
    union { unsigned u; float f; } x; x.u = ((unsigned)v) << 16; return x.f;
}
static __device__ __forceinline__ u16 f2b(float f) {
    union { float f; unsigned u; } x; x.f = f;
    unsigned u = x.u;
    return (u16)((u + 0x7fffu + ((u >> 16) & 1u)) >> 16);
}

#define GLOAD_LDS16(g, l) __builtin_amdgcn_global_load_lds( \
    (const __attribute__((address_space(1))) void*)(g),     \
    (__attribute__((address_space(3))) void*)(l), 16, 0, 0)

// ================= D1: count_deg (blocks 0..cblk-1) + detect (block cblk) ==========
__global__ __launch_bounds__(256) void k_detect_count(
    const int* __restrict__ dst, int E, int Nn, int* __restrict__ deg, int cblk,
    const u16* p0, const u16* p1, const u16* p2, const u16* p3, const u16* p4,
    int n0, int n1, int n2, int n3, int n4, int* __restrict__ flags) {
    const int b = blockIdx.x;
    if (b < cblk) {
        int e = b * 256 + threadIdx.x;
        if (e < E) {
            int d = dst[e];
            if ((unsigned)d < (unsigned)Nn) atomicAdd(&deg[d], 1);
        }
        return;
    }
    // detect: even u16 halves of fp32 data are mantissa garbage; |bf16|>=64
    // occurs w.p. ~0.44/sample for fp32, never for this problem's bf16 values.
    const u16* P[5] = {p0, p1, p2, p3, p4};
    const int N[5] = {n0, n1, n2, n3, n4};
    __shared__ int any[5];
    if (threadIdx.x < 5) any[threadIdx.x] = 0;
    __syncthreads();
    for (int t = 0; t < 5; ++t) {
        const u16* p = P[t];
        const int lim = N[t] < 512 ? N[t] : 512;
        int found = 0;
        for (int j = threadIdx.x; 2 * j < lim; j += 256) {
            unsigned v = p[2 * j] & 0x7fffu;
            if (v >= 0x4280u) found = 1;
        }
        if (found) atomicOr(&any[t], 1);
    }
    __syncthreads();
    if (threadIdx.x < 5) flags[threadIdx.x] = any[threadIdx.x];
}

// ================= D2: all conversions + scan =====================================
// blocks [0,nHb): Hb cvt | [nHb,+512): W1T | [+512,+640): W2T | +640: biases | +641: scan
__device__ __forceinline__ void cvt_wt_dev(const void* __restrict__ W, int f,
                                           u16* __restrict__ Wt, int Nw,
                                           int koff, int noff, int bx, int by,
                                           u16 (*tile)[33]) {
    const int tx = threadIdx.x & 31, ty = threadIdx.x >> 5;
    for (int i = ty; i < 32; i += 8) {
        long idx = (long)(koff + by + i) * Nw + (bx + tx);
        tile[i][tx] = f ? f2b(((const float*)W)[idx]) : ((const u16*)W)[idx];
    }
    __syncthreads();
    for (int i = ty; i < 32; i += 8)
        Wt[(long)(noff + bx + i) * 512 + (by + tx)] = tile[tx][i];
}

__global__ __launch_bounds__(256) void k_prep(
    const void* __restrict__ h, const void* __restrict__ W1,
    const void* __restrict__ b1, const void* __restrict__ W2,
    const void* __restrict__ b2, const int* __restrict__ flags,
    u16* __restrict__ Hb, u16* __restrict__ W1T, u16* __restrict__ W2T,
    u16* __restrict__ b1c, u16* __restrict__ b2c,
    const int* __restrict__ deg, int* __restrict__ ofs, int Nn, int nHb) {
    __shared__ u16 tile[32][33];
    __shared__ int part[256];
    const int b = blockIdx.x;
    const int t = threadIdx.x;
    if (b < nHb) {
        int i = (b * 256 + t) * 8;
        if (i >= Nn * 512) return;
        if (flags[0]) {
            const float* s = (const float*)h;
            us8 o;
#pragma unroll
            for (int k = 0; k < 8; ++k) o[k] = f2b(s[i + k]);
            *(us8*)(Hb + i) = o;
        } else {
            *(us8*)(Hb + i) = *(const us8*)((const u16*)h + i);
        }
        return;
    }
    if (b < nHb + 512) {  // W1 [1024,512] -> W1T [1024,512] (self rows 0.., agg 512..)
        int sub = b - nHb;
        int half = sub >> 8;            // 0 or 1
        int idx = sub & 255;            // 16x16 tiles
        cvt_wt_dev(W1, flags[1], W1T, 512, half * 512, half * 512,
                   (idx & 15) * 32, (idx >> 4) * 32, tile);
        return;
    }
    if (b < nHb + 640) {  // W2 [1024,128] -> W2T [256,512]
        int sub = b - nHb - 512;
        int half = sub >> 6;            // 0 or 1
        int idx = sub & 63;             // 4x16 tiles
        cvt_wt_dev(W2, flags[3], W2T, 128, half * 512, half * 128,
                   (idx & 3) * 32, (idx >> 2) * 32, tile);
        return;
    }
    if (b == nHb + 640) {  // biases
        for (int i = t; i < 512; i += 256)
            b1c[i] = flags[2] ? f2b(((const float*)b1)[i]) : ((const u16*)b1)[i];
        if (t < 128)
            b2c[t] = flags[4] ? f2b(((const float*)b2)[t]) : ((const u16*)b2)[t];
        return;
    }
    // scan (256-thread Hillis-Steele over per-thread chunks)
    {
        const int CH = (Nn + 255) / 256;
        const int base = t * CH;
        int s = 0;
        for (int i = 0; i < CH; ++i) { int idx = base + i; if (idx < Nn) s += deg[idx]; }
        part[t] = s;
        __syncthreads();
        for (int off = 1; off < 256; off <<= 1) {
            int u = (t >= off) ? part[t - off] : 0;
            __syncthreads();
            part[t] += u;
            __syncthreads();
        }
        int run = (t == 0) ? 0 : part[t - 1];
        for (int i = 0; i < CH; ++i) {
            int idx = base + i;
            if (idx < Nn) { ofs[idx] = run; run += deg[idx]; }
        }
        if (t == 255) ofs[Nn] = part[255];
    }
}

// ================= GEMM tile (device) =============================================
// C_tile = A[brow:+128, 0:512] @ Bt[bcol:+128, 0:512]^T ; bf16 out at C+coff, ld ldc
__device__ __forceinline__ void gemm_tile(const u16* __restrict__ A,
                                          const u16* __restrict__ Bt,
                                          u16* __restrict__ C, int ldc, int coff,
                                          long brow, int bcol, int Mstore,
                                          u16* lA, u16* lB) {
    const int tid = threadIdx.x;
    const int wv = tid >> 6;
    const int ln = tid & 63;
    const int wr = (wv >> 1) * 64;
    const int wc = (wv & 1) * 64;
    const int lrow = ln >> 2;
    const int lk = (ln & 3) * 8;
    const int m0 = ln & 15;
    const int kq = (ln >> 4) * 8;

    floatx4 acc[4][4];
#pragma unroll
    for (int i = 0; i < 4; ++i)
#pragma unroll
        for (int j = 0; j < 4; ++j) acc[i][j] = (floatx4){0.f, 0.f, 0.f, 0.f};

    for (int kt = 0; kt < 512; kt += 32) {
#pragma unroll
        for (int i = 0; i < 2; ++i) {
            const int c = i * 4 + wv;
            const int row = c * 16 + lrow;
            GLOAD_LDS16(A + (brow + row) * 512 + kt + lk, lA + c * 512);
            GLOAD_LDS16(Bt + (long)(bcol + row) * 512 + kt + lk, lB + c * 512);
        }
        __syncthreads();
        bf16x8 af[4], bf[4];
#pragma unroll
        for (int i = 0; i < 4; ++i)
            af[i] = *(const bf16x8*)(lA + (wr + i * 16 + m0) * 32 + kq);
#pragma unroll
        for (int j = 0; j < 4; ++j)
            bf[j] = *(const bf16x8*)(lB + (wc + j * 16 + m0) * 32 + kq);
#pragma unroll
        for (int i = 0; i < 4; ++i)
#pragma unroll
            for (int j = 0; j < 4; ++j)
                acc[i][j] = __builtin_amdgcn_mfma_f32_16x16x32_bf16(af[i], bf[j],
                                                                    acc[i][j], 0, 0, 0);
        __syncthreads();
    }

    const int q4 = (ln >> 4) * 4;
#pragma unroll
    for (int i = 0; i < 4; ++i) {
#pragma unroll
        for (int r = 0; r < 4; ++r) {
            long row = brow + wr + i * 16 + q4 + r;
            if (row < Mstore) {
#pragma unroll
                for (int j = 0; j < 4; ++j)
                    C[row * (long)ldc + (coff + wc + j * 16 + m0)] = f2b(acc[i][j][r]);
            }
        }
    }
}

// ================= D3: fill_csr (blocks 0..fblk-1) + GEMM1 ========================
__global__ __launch_bounds__(256) void k_fill_gemm1(
    const int* __restrict__ src, const int* __restrict__ dst, int E, int Nn,
    const int* __restrict__ ofs, int* __restrict__ deg, int* __restrict__ esrc,
    const u16* __restrict__ A, const u16* __restrict__ Bt,
    u16* __restrict__ C1s, u16* __restrict__ P1, int fblk, int mtiles, int Mstore) {
    __shared__ __align__(16) u16 lA[128 * 32];
    __shared__ __align__(16) u16 lB[128 * 32];
    const int b = blockIdx.x;
    if (b < fblk) {
        int e = b * 256 + threadIdx.x;
        if (e < E) {
            int d = dst[e];
            if ((unsigned)d < (unsigned)Nn) {
                int p = atomicAdd(&deg[d], -1);  // counts down; deg dead after
                esrc[ofs[d] + p - 1] = src[e];
            }
        }
        return;
    }
    const int g = b - fblk;
    const int bx = g % mtiles;
    const int by = g / mtiles;          // 0..7 ; cols [by*128, +128)
    const int bcol = by * 128;
    u16* C = (by < 4) ? C1s : P1;
    const int coff = (by < 4) ? bcol : bcol - 512;
    gemm_tile(A, Bt, C, 512, coff, (long)bx * 128, bcol, Mstore, lA, lB);
}

// ================= D5: GEMM2 ======================================================
__global__ __launch_bounds__(256) void k_gemm2(
    const u16* __restrict__ A, const u16* __restrict__ Bt,
    u16* __restrict__ C2s, u16* __restrict__ P2, int Mstore) {
    __shared__ __align__(16) u16 lA[128 * 32];
    __shared__ __align__(16) u16 lB[128 * 32];
    const int by = blockIdx.y;          // 0: self, 1: agg
    u16* C = by ? P2 : C2s;
    gemm_tile(A, Bt, C, 128, 0, (long)blockIdx.x * 128, by * 128, Mstore, lA, lB);
}

// ================= D4: h1 = relu(C1s + mean(P1[nbrs]) + b1) =======================
// 256 threads = 2 nodes; 4 cols/thread; 4-deep gather unroll
__global__ __launch_bounds__(256) void agg_h1(const u16* __restrict__ P1,
                                              const u16* __restrict__ C1s,
                                              const u16* __restrict__ b1c,
                                              const int* __restrict__ ofs,
                                              const int* __restrict__ esrc,
                                              u16* __restrict__ h1, int Nn) {
    const int n = blockIdx.x * 2 + (threadIdx.x >> 7);
    const int t = threadIdx.x & 127;
    if (n >= Nn) return;
    const int beg = ofs[n], end = ofs[n + 1];
    float a0 = 0.f, a1 = 0.f, a2 = 0.f, a3 = 0.f;
    int e = beg;
    for (; e + 3 < end; e += 4) {
        int s0 = esrc[e], s1 = esrc[e + 1], s2 = esrc[e + 2], s3 = esrc[e + 3];
        if ((unsigned)s0 >= (unsigned)Nn) s0 = 0;
        if ((unsigned)s1 >= (unsigned)Nn) s1 = 0;
        if ((unsigned)s2 >= (unsigned)Nn) s2 = 0;
        if ((unsigned)s3 >= (unsigned)Nn) s3 = 0;
        us4 v0 = *(const us4*)(P1 + (long)s0 * 512 + t * 4);
        us4 v1 = *(const us4*)(P1 + (long)s1 * 512 + t * 4);
        us4 v2 = *(const us4*)(P1 + (long)s2 * 512 + t * 4);
        us4 v3 = *(const us4*)(P1 + (long)s3 * 512 + t * 4);
        a0 += (b2f(v0[0]) + b2f(v1[0])) + (b2f(v2[0]) + b2f(v3[0]));
        a1 += (b2f(v0[1]) + b2f(v1[1])) + (b2f(v2[1]) + b2f(v3[1]));
        a2 += (b2f(v0[2]) + b2f(v1[2])) + (b2f(v2[2]) + b2f(v3[2]));
        a3 += (b2f(v0[3]) + b2f(v1[3])) + (b2f(v2[3]) + b2f(v3[3]));
    }
    for (; e < end; ++e) {
        int s0 = esrc[e];
        if ((unsigned)s0 >= (unsigned)Nn) s0 = 0;
        us4 v0 = *(const us4*)(P1 + (long)s0 * 512 + t * 4);
        a0 += b2f(v0[0]); a1 += b2f(v0[1]); a2 += b2f(v0[2]); a3 += b2f(v0[3]);
    }
    int d = end - beg;
    float inv = 1.0f / (float)(d > 1 ? d : 1);
    us4 sf = *(const us4*)(C1s + (long)n * 512 + t * 4);
    us4 bv = *(const us4*)(b1c + t * 4);
    us4 o;
    o[0] = f2b(fmaxf(b2f(sf[0]) + a0 * inv + b2f(bv[0]), 0.f));
    o[1] = f2b(fmaxf(b2f(sf[1]) + a1 * inv + b2f(bv[1]), 0.f));
    o[2] = f2b(fmaxf(b2f(sf[2]) + a2 * inv + b2f(bv[2]), 0.f));
    o[3] = f2b(fmaxf(b2f(sf[3]) + a3 * inv + b2f(bv[3]), 0.f));
    *(us4*)(h1 + (long)n * 512 + t * 4) = o;
}

// ================= D6: out = C2s + mean(P2[nbrs]) + b2 ============================
// 256 threads = 4 nodes; 2 cols/lane; 4-deep gather unroll
__global__ __launch_bounds__(256) void agg_out(const u16* __restrict__ P2,
                                               const u16* __restrict__ C2s,
                                               const u16* __restrict__ b2c,
                                               const int* __restrict__ ofs,
                                               const int* __restrict__ esrc,
                                               void* __restrict__ outv, int Nn,
                                               const int* __restrict__ flag) {
    const int n = blockIdx.x * 4 + (threadIdx.x >> 6);
    const int l = threadIdx.x & 63;
    if (n >= Nn) return;
    const int beg = ofs[n], end = ofs[n + 1];
    float a0 = 0.f, a1 = 0.f;
    int e = beg;
    for (; e + 3 < end; e += 4) {
        int s0 = esrc[e], s1 = esrc[e + 1], s2 = esrc[e + 2], s3 = esrc[e + 3];
        if ((unsigned)s0 >= (unsigned)Nn) s0 = 0;
        if ((unsigned)s1 >= (unsigned)Nn) s1 = 0;
        if ((unsigned)s2 >= (unsigned)Nn) s2 = 0;
        if ((unsigned)s3 >= (unsigned)Nn) s3 = 0;
        us2 v0 = *(const us2*)(P2 + (long)s0 * 128 + l * 2);
        us2 v1 = *(const us2*)(P2 + (long)s1 * 128 + l * 2);
        us2 v2 = *(const us2*)(P2 + (long)s2 * 128 + l * 2);
        us2 v3 = *(const us2*)(P2 + (long)s3 * 128 + l * 2);
        a0 += (b2f(v0[0]) + b2f(v1[0])) + (b2f(v2[0]) + b2f(v3[0]));
        a1 += (b2f(v0[1]) + b2f(v1[1])) + (b2f(v2[1]) + b2f(v3[1]));
    }
    for (; e < end; ++e) {
        int s0 = esrc[e];
        if ((unsigned)s0 >= (unsigned)Nn) s0 = 0;
        us2 v0 = *(const us2*)(P2 + (long)s0 * 128 + l * 2);
        a0 += b2f(v0[0]); a1 += b2f(v0[1]);
    }
    int d = end - beg;
    float inv = 1.0f / (float)(d > 1 ? d : 1);
    us2 sf = *(const us2*)(C2s + (long)n * 128 + l * 2);
    us2 bv = *(const us2*)(b2c + l * 2);
    float o0 = b2f(sf[0]) + a0 * inv + b2f(bv[0]);
    float o1 = b2f(sf[1]) + a1 * inv + b2f(bv[1]);
    if (*flag) {
        float* o = (float*)outv + (long)n * 128 + l * 2;
        o[0] = o0; o[1] = o1;
    } else {
        us2 ob; ob[0] = f2b(o0); ob[1] = f2b(o1);
        *(us2*)((u16*)outv + (long)n * 128 + l * 2) = ob;
    }
}

// ================= launch =========================================================
extern "C" void kernel_launch(void* const* d_in, const int* in_sizes, int n_in,
                              void* d_out, int out_size, void* d_ws, size_t ws_size,
                              hipStream_t stream) {
    const int D = 512, NCLS = 128;
    const int Nn = in_sizes[0] / D;          // 10000
    const int E  = in_sizes[5];              // 160000
    const int mtiles = (Nn + 127) / 128;     // 79
    const int Mpad = mtiles * 128;           // 10112
    const int cblk = (E + 255) / 256;        // 625
    const int nHb = (Nn * D / 8 + 255) / 256;  // 2500

    const int* src = (const int*)d_in[5];
    const int* dst = (const int*)d_in[6];

    char* p = (char*)d_ws;
    u16* Hb  = (u16*)p; p += (size_t)Mpad * D * 2;
    u16* h1  = (u16*)p; p += (size_t)Mpad * D * 2;
    u16* C1s = (u16*)p; p += (size_t)Mpad * D * 2;
    u16* P1  = (u16*)p; p += (size_t)Mpad * D * 2;
    u16* C2s = (u16*)p; p += (size_t)Mpad * NCLS * 2;
    u16* P2  = (u16*)p; p += (size_t)Mpad * NCLS * 2;
    u16* W1T = (u16*)p; p += (size_t)1024 * D * 2;
    u16* W2T = (u16*)p; p += (size_t)256 * D * 2;
    u16* b1c = (u16*)p; p += 1024;
    u16* b2c = (u16*)p; p += 1024;
    int* flags  = (int*)p; p += 256;
    int* deg    = (int*)p; p += (size_t)(Nn + 64) * 4;
    int* ofs    = (int*)p; p += (size_t)(Nn + 64) * 4;
    int* esrc   = (int*)p; p += (size_t)E * 4;

    hipMemsetAsync(deg, 0, (size_t)(Nn + 64) * 4, stream);

    // D1: count + detect
    k_detect_count<<<cblk + 1, 256, 0, stream>>>(
        dst, E, Nn, deg, cblk,
        (const u16*)d_in[0], (const u16*)d_in[1], (const u16*)d_in[2],
        (const u16*)d_in[3], (const u16*)d_in[4],
        in_sizes[0], in_sizes[1], in_sizes[2], in_sizes[3], in_sizes[4], flags);

    // D2: conversions + scan
    k_prep<<<nHb + 642, 256, 0, stream>>>(
        d_in[0], d_in[1], d_in[2], d_in[3], d_in[4], flags,
        Hb, W1T, W2T, b1c, b2c, deg, ofs, Nn, nHb);

    // D3: fill + GEMM1 ([C1s|P1] = Hb @ W1T^T)
    k_fill_gemm1<<<cblk + mtiles * 8, 256, 0, stream>>>(
        src, dst, E, Nn, ofs, deg, esrc, Hb, W1T, C1s, P1, cblk, mtiles, Nn);

    // D4: h1 = relu(C1s + mean(P1[nbrs]) + b1)
    agg_h1<<<(Nn + 1) / 2, 256, 0, stream>>>(P1, C1s, b1c, ofs, esrc, h1, Nn);

    // D5: [C2s|P2] = h1 @ W2T^T
    k_gemm2<<<dim3(mtiles, 2), 256, 0, stream>>>(h1, W2T, C2s, P2, Nn);

    // D6: out = C2s + mean(P2[nbrs]) + b2
    agg_out<<<(Nn + 3) / 4, 256, 0, stream>>>(P2, C2s, b2c, ofs, esrc, d_out, Nn, flags);
}

// Round 6
// 161.547 us; speedup vs baseline: 4.0218x; 1.1689x over previous
//
#include <hip/hip_runtime.h>

typedef unsigned short u16;
typedef __attribute__((ext_vector_type(4))) float floatx4;
typedef __attribute__((ext_vector_type(8))) __bf16 bf16x8;
typedef __attribute__((ext_vector_type(2))) unsigned short us2;
typedef __attribute__((ext_vector_type(4))) unsigned short us4;
typedef __attribute__((ext_vector_type(8))) unsigned short us8;

static __device__ __forceinline__ float b2f(u16 v) {
    union { unsigned u; float f; } x; x.u = ((unsigned)v) << 16; return x.f;
}
static __device__ __forceinline__ u16 f2b(float f) {
    union { float f; unsigned u; } x; x.f = f;
    unsigned u = x.u;
    return (u16)((u + 0x7fffu + ((u >> 16) & 1u)) >> 16);
}

#define GLOAD_LDS16(g, l) __builtin_amdgcn_global_load_lds( \
    (const __attribute__((address_space(1))) void*)(g),     \
    (__attribute__((address_space(3))) void*)(l), 16, 0, 0)

#define CAP 64
#define SPILLMAX 4096

// Per-block dtype self-detection: sample the tensor head's even u16s.
// fp32 data -> those are low mantissa halves, log-uniform as bf16 (|x|>=64
// w.p. ~0.44/sample). This problem's bf16 values are all < 64. 256 samples
// -> P(misdetect fp32 as bf16) ~ 0.56^256 ~ 1e-65. Bounds-safe: index 2j < n
// is in-range for bf16 (n u16s) and fp32 (2n u16s) alike.
static __device__ __forceinline__ int detect_blk(const u16* __restrict__ p,
                                                 int nelem, int* sh) {
    if (threadIdx.x == 0) *sh = 0;
    __syncthreads();
    const int lim = nelem < 512 ? nelem : 512;
    int found = 0;
    for (int j = threadIdx.x; 2 * j < lim; j += 256) {
        unsigned v = p[2 * j] & 0x7fffu;
        if (v >= 0x4280u) found = 1;  // |bf16(bits)| >= 64.0
    }
    if (found) atomicOr(sh, 1);
    __syncthreads();
    return *sh;
}

// ================= D1: buckets + all conversions (self-detecting) ================
// blocks: [0,nFill): bucket fill | [nFill,+nHb): Hb cvt | +512: W1T | +128: W2T
//         | last: biases + out-flag
__global__ __launch_bounds__(256) void k_d1(
    const int* __restrict__ src, const int* __restrict__ dst, int E, int Nn,
    int* __restrict__ cnt, int* __restrict__ bucket,
    int* __restrict__ nspill, int* __restrict__ spill,
    const void* __restrict__ h, const void* __restrict__ W1,
    const void* __restrict__ b1, const void* __restrict__ W2,
    const void* __restrict__ b2,
    u16* __restrict__ Hb, u16* __restrict__ W1T, u16* __restrict__ W2T,
    u16* __restrict__ b1c, u16* __restrict__ b2c, int* __restrict__ flags,
    int nFill, int nHb) {
    __shared__ u16 tile[32][33];
    __shared__ int sh;
    const int b = blockIdx.x;
    const int t = threadIdx.x;

    if (b < nFill) {  // -------- bucket fill --------
        int e = b * 256 + t;
        if (e < E) {
            int d = dst[e], s = src[e];
            if ((unsigned)d < (unsigned)Nn && (unsigned)s < (unsigned)Nn) {
                int p = atomicAdd(&cnt[d], 1);
                if (p < CAP) bucket[d * CAP + p] = s;
                else {
                    int q = atomicAdd(nspill, 1);
                    if (q < SPILLMAX) { spill[2 * q] = d; spill[2 * q + 1] = s; }
                }
            }
        }
        return;
    }
    if (b < nFill + nHb) {  // -------- Hb cvt --------
        const int f = detect_blk((const u16*)h, Nn * 512, &sh);
        int i = ((b - nFill) * 256 + t) * 8;
        if (i >= Nn * 512) return;
        if (f) {
            const float* s = (const float*)h;
            us8 o;
#pragma unroll
            for (int k = 0; k < 8; ++k) o[k] = f2b(s[i + k]);
            *(us8*)(Hb + i) = o;
        } else {
            *(us8*)(Hb + i) = *(const us8*)((const u16*)h + i);
        }
        return;
    }
    if (b < nFill + nHb + 512) {  // -------- W1 [1024,512] -> W1T [1024,512] --------
        const int f = detect_blk((const u16*)W1, 1024 * 512, &sh);
        int sub = b - nFill - nHb;
        int half = sub >> 8, idx = sub & 255;
        const int bx = (idx & 15) * 32, by = (idx >> 4) * 32;
        const int koff = half * 512, noff = half * 512;
        const int tx = t & 31, ty = t >> 5;
        for (int i = ty; i < 32; i += 8) {
            long id = (long)(koff + by + i) * 512 + (bx + tx);
            tile[i][tx] = f ? f2b(((const float*)W1)[id]) : ((const u16*)W1)[id];
        }
        __syncthreads();
        for (int i = ty; i < 32; i += 8)
            W1T[(long)(noff + bx + i) * 512 + (by + tx)] = tile[tx][i];
        return;
    }
    if (b < nFill + nHb + 640) {  // -------- W2 [1024,128] -> W2T [256,512] --------
        const int f = detect_blk((const u16*)W2, 1024 * 128, &sh);
        int sub = b - nFill - nHb - 512;
        int half = sub >> 6, idx = sub & 63;
        const int bx = (idx & 3) * 32, by = (idx >> 2) * 32;
        const int koff = half * 512, noff = half * 128;
        const int tx = t & 31, ty = t >> 5;
        for (int i = ty; i < 32; i += 8) {
            long id = (long)(koff + by + i) * 128 + (bx + tx);
            tile[i][tx] = f ? f2b(((const float*)W2)[id]) : ((const u16*)W2)[id];
        }
        __syncthreads();
        for (int i = ty; i < 32; i += 8)
            W2T[(long)(noff + bx + i) * 512 + (by + tx)] = tile[tx][i];
        return;
    }
    // -------- biases + out-dtype flag --------
    {
        const int f1 = detect_blk((const u16*)b1, 512, &sh);
        for (int i = t; i < 512; i += 256)
            b1c[i] = f1 ? f2b(((const float*)b1)[i]) : ((const u16*)b1)[i];
        const int f2 = detect_blk((const u16*)b2, 128, &sh);
        if (t < 128)
            b2c[t] = f2 ? f2b(((const float*)b2)[t]) : ((const u16*)b2)[t];
        const int fh = detect_blk((const u16*)h, Nn * 512, &sh);
        if (t == 0) flags[0] = fh;
    }
}

// ================= GEMM tile (device) ============================================
// C_tile = A[brow:+128, 0:512] @ Bt[bcol:+128, 0:512]^T ; bf16 out
__device__ __forceinline__ void gemm_tile(const u16* __restrict__ A,
                                          const u16* __restrict__ Bt,
                                          u16* __restrict__ C, int ldc, int coff,
                                          long brow, int bcol, int Mstore,
                                          u16* lA, u16* lB) {
    const int tid = threadIdx.x;
    const int wv = tid >> 6;
    const int ln = tid & 63;
    const int wr = (wv >> 1) * 64;
    const int wc = (wv & 1) * 64;
    const int lrow = ln >> 2;
    const int lk = (ln & 3) * 8;
    const int m0 = ln & 15;
    const int kq = (ln >> 4) * 8;

    floatx4 acc[4][4];
#pragma unroll
    for (int i = 0; i < 4; ++i)
#pragma unroll
        for (int j = 0; j < 4; ++j) acc[i][j] = (floatx4){0.f, 0.f, 0.f, 0.f};

    for (int kt = 0; kt < 512; kt += 32) {
#pragma unroll
        for (int i = 0; i < 2; ++i) {
            const int c = i * 4 + wv;
            const int row = c * 16 + lrow;
            GLOAD_LDS16(A + (brow + row) * 512 + kt + lk, lA + c * 512);
            GLOAD_LDS16(Bt + (long)(bcol + row) * 512 + kt + lk, lB + c * 512);
        }
        __syncthreads();
        bf16x8 af[4], bf[4];
#pragma unroll
        for (int i = 0; i < 4; ++i)
            af[i] = *(const bf16x8*)(lA + (wr + i * 16 + m0) * 32 + kq);
#pragma unroll
        for (int j = 0; j < 4; ++j)
            bf[j] = *(const bf16x8*)(lB + (wc + j * 16 + m0) * 32 + kq);
#pragma unroll
        for (int i = 0; i < 4; ++i)
#pragma unroll
            for (int j = 0; j < 4; ++j)
                acc[i][j] = __builtin_amdgcn_mfma_f32_16x16x32_bf16(af[i], bf[j],
                                                                    acc[i][j], 0, 0, 0);
        __syncthreads();
    }

    const int q4 = (ln >> 4) * 4;
#pragma unroll
    for (int i = 0; i < 4; ++i) {
#pragma unroll
        for (int r = 0; r < 4; ++r) {
            long row = brow + wr + i * 16 + q4 + r;
            if (row < Mstore) {
#pragma unroll
                for (int j = 0; j < 4; ++j)
                    C[row * (long)ldc + (coff + wc + j * 16 + m0)] = f2b(acc[i][j][r]);
            }
        }
    }
}

// ================= D2: GEMM1 ([C1s|P1] = Hb @ W1T^T) =============================
__global__ __launch_bounds__(256) void k_gemm1(
    const u16* __restrict__ A, const u16* __restrict__ Bt,
    u16* __restrict__ C1s, u16* __restrict__ P1, int Mstore) {
    __shared__ __align__(16) u16 lA[128 * 32];
    __shared__ __align__(16) u16 lB[128 * 32];
    const int by = blockIdx.y;          // 0..7
    const int bcol = by * 128;
    u16* C = (by < 4) ? C1s : P1;
    const int coff = (by < 4) ? bcol : bcol - 512;
    gemm_tile(A, Bt, C, 512, coff, (long)blockIdx.x * 128, bcol, Mstore, lA, lB);
}

// ================= D4: GEMM2 ([C2s|P2] = h1 @ W2T^T) =============================
__global__ __launch_bounds__(256) void k_gemm2(
    const u16* __restrict__ A, const u16* __restrict__ Bt,
    u16* __restrict__ C2s, u16* __restrict__ P2, int Mstore) {
    __shared__ __align__(16) u16 lA[128 * 32];
    __shared__ __align__(16) u16 lB[128 * 32];
    const int by = blockIdx.y;          // 0: self, 1: agg
    u16* C = by ? P2 : C2s;
    gemm_tile(A, Bt, C, 128, 0, (long)blockIdx.x * 128, by * 128, Mstore, lA, lB);
}

// ================= D3: h1 = relu(C1s + mean(P1[nbrs]) + b1) ======================
// 256 threads = 2 nodes; 4 cols/thread; 4-deep gather unroll; bucket CSR
__global__ __launch_bounds__(256) void agg_h1(const u16* __restrict__ P1,
                                              const u16* __restrict__ C1s,
                                              const u16* __restrict__ b1c,
                                              const int* __restrict__ cnt,
                                              const int* __restrict__ bucket,
                                              const int* __restrict__ nspill,
                                              const int* __restrict__ spill,
                                              u16* __restrict__ h1, int Nn) {
    const int n = blockIdx.x * 2 + (threadIdx.x >> 7);
    const int t = threadIdx.x & 127;
    if (n >= Nn) return;
    const int c = cnt[n];
    const int inb = c < CAP ? c : CAP;
    const int* bk = bucket + (long)n * CAP;
    float a0 = 0.f, a1 = 0.f, a2 = 0.f, a3 = 0.f;
    int e = 0;
    for (; e + 3 < inb; e += 4) {
        int s0 = bk[e], s1 = bk[e + 1], s2 = bk[e + 2], s3 = bk[e + 3];
        us4 v0 = *(const us4*)(P1 + (long)s0 * 512 + t * 4);
        us4 v1 = *(const us4*)(P1 + (long)s1 * 512 + t * 4);
        us4 v2 = *(const us4*)(P1 + (long)s2 * 512 + t * 4);
        us4 v3 = *(const us4*)(P1 + (long)s3 * 512 + t * 4);
        a0 += (b2f(v0[0]) + b2f(v1[0])) + (b2f(v2[0]) + b2f(v3[0]));
        a1 += (b2f(v0[1]) + b2f(v1[1])) + (b2f(v2[1]) + b2f(v3[1]));
        a2 += (b2f(v0[2]) + b2f(v1[2])) + (b2f(v2[2]) + b2f(v3[2]));
        a3 += (b2f(v0[3]) + b2f(v1[3])) + (b2f(v2[3]) + b2f(v3[3]));
    }
    for (; e < inb; ++e) {
        int s0 = bk[e];
        us4 v0 = *(const us4*)(P1 + (long)s0 * 512 + t * 4);
        a0 += b2f(v0[0]); a1 += b2f(v0[1]); a2 += b2f(v0[2]); a3 += b2f(v0[3]);
    }
    const int ns = *nspill;             // 0 in practice
    if (ns > 0) {
        int lim = ns < SPILLMAX ? ns : SPILLMAX;
        for (int q = 0; q < lim; ++q) {
            if (spill[2 * q] == n) {
                int s0 = spill[2 * q + 1];
                us4 v0 = *(const us4*)(P1 + (long)s0 * 512 + t * 4);
                a0 += b2f(v0[0]); a1 += b2f(v0[1]); a2 += b2f(v0[2]); a3 += b2f(v0[3]);
            }
        }
    }
    float inv = 1.0f / (float)(c > 1 ? c : 1);
    us4 sf = *(const us4*)(C1s + (long)n * 512 + t * 4);
    us4 bv = *(const us4*)(b1c + t * 4);
    us4 o;
    o[0] = f2b(fmaxf(b2f(sf[0]) + a0 * inv + b2f(bv[0]), 0.f));
    o[1] = f2b(fmaxf(b2f(sf[1]) + a1 * inv + b2f(bv[1]), 0.f));
    o[2] = f2b(fmaxf(b2f(sf[2]) + a2 * inv + b2f(bv[2]), 0.f));
    o[3] = f2b(fmaxf(b2f(sf[3]) + a3 * inv + b2f(bv[3]), 0.f));
    *(us4*)(h1 + (long)n * 512 + t * 4) = o;
}

// ================= D5: out = C2s + mean(P2[nbrs]) + b2 ===========================
// 256 threads = 4 nodes; 2 cols/lane; 4-deep gather unroll; bucket CSR
__global__ __launch_bounds__(256) void agg_out(const u16* __restrict__ P2,
                                               const u16* __restrict__ C2s,
                                               const u16* __restrict__ b2c,
                                               const int* __restrict__ cnt,
                                               const int* __restrict__ bucket,
                                               const int* __restrict__ nspill,
                                               const int* __restrict__ spill,
                                               void* __restrict__ outv, int Nn,
                                               const int* __restrict__ flags) {
    const int n = blockIdx.x * 4 + (threadIdx.x >> 6);
    const int l = threadIdx.x & 63;
    if (n >= Nn) return;
    const int c = cnt[n];
    const int inb = c < CAP ? c : CAP;
    const int* bk = bucket + (long)n * CAP;
    float a0 = 0.f, a1 = 0.f;
    int e = 0;
    for (; e + 3 < inb; e += 4) {
        int s0 = bk[e], s1 = bk[e + 1], s2 = bk[e + 2], s3 = bk[e + 3];
        us2 v0 = *(const us2*)(P2 + (long)s0 * 128 + l * 2);
        us2 v1 = *(const us2*)(P2 + (long)s1 * 128 + l * 2);
        us2 v2 = *(const us2*)(P2 + (long)s2 * 128 + l * 2);
        us2 v3 = *(const us2*)(P2 + (long)s3 * 128 + l * 2);
        a0 += (b2f(v0[0]) + b2f(v1[0])) + (b2f(v2[0]) + b2f(v3[0]));
        a1 += (b2f(v0[1]) + b2f(v1[1])) + (b2f(v2[1]) + b2f(v3[1]));
    }
    for (; e < inb; ++e) {
        int s0 = bk[e];
        us2 v0 = *(const us2*)(P2 + (long)s0 * 128 + l * 2);
        a0 += b2f(v0[0]); a1 += b2f(v0[1]);
    }
    const int ns = *nspill;
    if (ns > 0) {
        int lim = ns < SPILLMAX ? ns : SPILLMAX;
        for (int q = 0; q < lim; ++q) {
            if (spill[2 * q] == n) {
                int s0 = spill[2 * q + 1];
                us2 v0 = *(const us2*)(P2 + (long)s0 * 128 + l * 2);
                a0 += b2f(v0[0]); a1 += b2f(v0[1]);
            }
        }
    }
    float inv = 1.0f / (float)(c > 1 ? c : 1);
    us2 sf = *(const us2*)(C2s + (long)n * 128 + l * 2);
    us2 bv = *(const us2*)(b2c + l * 2);
    float o0 = b2f(sf[0]) + a0 * inv + b2f(bv[0]);
    float o1 = b2f(sf[1]) + a1 * inv + b2f(bv[1]);
    if (flags[0]) {
        float* o = (float*)outv + (long)n * 128 + l * 2;
        o[0] = o0; o[1] = o1;
    } else {
        us2 ob; ob[0] = f2b(o0); ob[1] = f2b(o1);
        *(us2*)((u16*)outv + (long)n * 128 + l * 2) = ob;
    }
}

// ================= launch ========================================================
extern "C" void kernel_launch(void* const* d_in, const int* in_sizes, int n_in,
                              void* d_out, int out_size, void* d_ws, size_t ws_size,
                              hipStream_t stream) {
    const int D = 512, NCLS = 128;
    const int Nn = in_sizes[0] / D;            // 10000
    const int E  = in_sizes[5];                // 160000
    const int mtiles = (Nn + 127) / 128;       // 79
    const int Mpad = mtiles * 128;             // 10112
    const int nFill = (E + 255) / 256;         // 625
    const int nHb = (Nn * D / 8 + 255) / 256;  // 2500

    const int* src = (const int*)d_in[5];
    const int* dst = (const int*)d_in[6];

    char* p = (char*)d_ws;
    u16* Hb  = (u16*)p; p += (size_t)Mpad * D * 2;
    u16* h1  = (u16*)p; p += (size_t)Mpad * D * 2;
    u16* C1s = (u16*)p; p += (size_t)Mpad * D * 2;
    u16* P1  = (u16*)p; p += (size_t)Mpad * D * 2;
    u16* C2s = (u16*)p; p += (size_t)Mpad * NCLS * 2;
    u16* P2  = (u16*)p; p += (size_t)Mpad * NCLS * 2;
    u16* W1T = (u16*)p; p += (size_t)1024 * D * 2;
    u16* W2T = (u16*)p; p += (size_t)256 * D * 2;
    u16* b1c = (u16*)p; p += 1024;
    u16* b2c = (u16*)p; p += 1024;
    int* flags  = (int*)p; p += 256;
    int* cnt    = (int*)p; p += (size_t)(Nn + 60) * 4;  // cnt + nspill zeroed together
    int* nspill = cnt + Nn;
    int* bucket = (int*)p; p += (size_t)Nn * CAP * 4;
    int* spill  = (int*)p; p += (size_t)SPILLMAX * 2 * 4;

    // zero cnt + nspill (contiguous, ~40 KB)
    hipMemsetAsync(cnt, 0, (size_t)(Nn + 60) * 4, stream);

    // D1: buckets + all conversions (self-detecting dtype)
    k_d1<<<nFill + nHb + 641, 256, 0, stream>>>(
        src, dst, E, Nn, cnt, bucket, nspill, spill,
        d_in[0], d_in[1], d_in[2], d_in[3], d_in[4],
        Hb, W1T, W2T, b1c, b2c, flags, nFill, nHb);

    // D2: [C1s|P1] = Hb @ W1T^T
    k_gemm1<<<dim3(mtiles, 8), 256, 0, stream>>>(Hb, W1T, C1s, P1, Nn);

    // D3: h1 = relu(C1s + mean(P1[nbrs]) + b1)
    agg_h1<<<(Nn + 1) / 2, 256, 0, stream>>>(P1, C1s, b1c, cnt, bucket,
                                             nspill, spill, h1, Nn);

    // D4: [C2s|P2] = h1 @ W2T^T
    k_gemm2<<<dim3(mtiles, 2), 256, 0, stream>>>(h1, W2T, C2s, P2, Nn);

    // D5: out = C2s + mean(P2[nbrs]) + b2
    agg_out<<<(Nn + 3) / 4, 256, 0, stream>>>(P2, C2s, b2c, cnt, bucket,
                                              nspill, spill, d_out, Nn, flags);
}